// Round 16
// baseline (434.349 us; speedup 1.0000x reference)
//
#include <hip/hip_runtime.h>
#include <hip/hip_bf16.h>
#include <math.h>

// Sizes
#define B_    128
#define T_    12
#define J_    17
#define HID_  128
#define LH_   512
#define NC_   500

typedef short  bf16x8 __attribute__((ext_vector_type(8)));
typedef ushort u16x8  __attribute__((ext_vector_type(8)));
typedef float  f32x4  __attribute__((ext_vector_type(4)));

__constant__ int d_c0[38] = {15,13,16,14,11,5,6,5,5,6,7,8,1,0,0,1,2,3,4,
                             13,11,14,12,12,11,12,6,7,8,9,10,2,1,2,3,4,5,6};
__constant__ int d_c1[38] = {13,11,14,12,12,11,12,6,7,8,9,10,2,1,2,3,4,5,6,
                             15,13,16,14,11,5,6,5,5,6,7,8,1,0,0,1,2,3,4};

__device__ __forceinline__ float lrelu02(float x){ return x > 0.f ? x : 0.2f*x; }
__device__ __forceinline__ float sigmoidf_(float x){ return 1.f/(1.f+__expf(-x)); }
__device__ __forceinline__ ushort f2bf(float f){
  uint32_t u = __builtin_bit_cast(uint32_t, f);
  uint32_t r = (u + 0x7fffu + ((u >> 16) & 1u)) >> 16;
  return (ushort)r;
}
__device__ __forceinline__ float bf2f(ushort u){
  uint32_t v = ((uint32_t)u) << 16;
  return __builtin_bit_cast(float, v);
}
// async global->LDS, 16B per lane; LDS dest wave-uniform base (+lane*16 implicit)
__device__ __forceinline__ void llds16(const ushort* g, ushort* l){
  __builtin_amdgcn_global_load_lds(
      (const __attribute__((address_space(1))) void*)g,
      (__attribute__((address_space(3))) void*)l,
      16, 0, 0);
}

// ---- D1: independent front-end work in ONE dispatch ----
//   [0,512)         W2mT ; [512,768) W2tb ; [768,10496) Wih cast
//   [10496,11520)   Whh fragment-packed
//   [11520,11928)   gat1s_al ; [11928,15000) edge branch
//   [15000,15004)   W1e4[k] = {W1[k],W1[1024+k],W1[2048+k],b1[k]}
__global__ __launch_bounds__(256) void k_front1(const float* __restrict__ W2,
    const float* __restrict__ Wih_f, const float* __restrict__ Wih_b,
    const float* __restrict__ Whh_f, const float* __restrict__ Whh_b,
    const float* __restrict__ pose1, const float* __restrict__ pose2,
    const float* __restrict__ W1, const float* __restrict__ b1,
    const float* __restrict__ a_s1, const float* __restrict__ a_d1,
    const float* __restrict__ W_fc, const float* __restrict__ b_fc,
    const float* __restrict__ bn_g, const float* __restrict__ bn_b,
    const float* __restrict__ bn_m, const float* __restrict__ bn_v,
    ushort* __restrict__ W2mT, ushort* __restrict__ W2tb,
    ushort* __restrict__ Wbf, ushort* __restrict__ Whh_pk,
    float* __restrict__ rawh_p, float* __restrict__ al_s_p, float* __restrict__ al_d_p,
    ushort* __restrict__ fb, float4* __restrict__ W1e4)
{
  __shared__ ushort sh[64][68];
  __shared__ float rh[1024];
  __shared__ float nrm[38], ang[38];
  int tid = threadIdx.x;
  int bx = blockIdx.x;
  if (bx < 512){
    int idx = bx*256 + tid;
    int c = idx >> 10, k = idx & 1023;
    float s = 0.f;
    #pragma unroll
    for (int h = 0; h < 8; h++) s += W2[k*1024 + h*128 + c];
    W2mT[idx] = f2bf(s * 0.125f);
  } else if (bx < 768){
    int b2x = bx - 512;
    int k0 = (b2x >> 4)*64, n0 = (b2x & 15)*64;
    #pragma unroll
    for (int q = 0; q < 16; q++){
      int idx = tid + q*256;
      int kk = idx >> 6, nn = idx & 63;
      sh[nn][kk] = f2bf(W2[(size_t)(k0+kk)*1024 + n0+nn]);
    }
    __syncthreads();
    #pragma unroll
    for (int q = 0; q < 16; q++){
      int idx = tid + q*256;
      int nn = idx >> 6, kk = idx & 63;
      W2tb[(size_t)(n0+nn)*1024 + k0+kk] = sh[nn][kk];
    }
  } else if (bx < 10496){
    const int S = 2048*2432;
    int i4 = (bx - 768)*256 + tid;
    int idx = i4*4;
    if (idx >= 2*S) return;
    const float* src = (idx < S) ? (Wih_f + idx) : (Wih_b + (idx - S));
    float4 v = *(const float4*)src;
    ushort4 o;
    o.x = f2bf(v.x); o.y = f2bf(v.y); o.z = f2bf(v.z); o.w = f2bf(v.w);
    *(ushort4*)(Wbf + idx) = o;
  } else if (bx < 11520){
    int i = (bx - 10496)*256 + tid;
    int base = i*8;
    int dir = base >> 20;
    int idx8 = (base & 1048575) >> 3;
    int lane = idx8 & 63;
    int t1 = idx8 >> 6;
    int n  = t1 & 3;
    int t2 = t1 >> 2;
    int kk = t2 & 7;
    int t3 = t2 >> 3;
    int kg = t3 & 1;
    int nb = t3 >> 1;
    int col = nb*64 + n*16 + (lane & 15);
    int u = col >> 2, g = col & 3;
    int k = kg*256 + kk*32 + (lane >> 4)*8;
    const float* src = (dir ? Whh_b : Whh_f) + ((size_t)(g*512+u))*512 + k;
    float4 v0 = *(const float4*)src;
    float4 v1 = *(const float4*)(src+4);
    ushort av[8] = {f2bf(v0.x),f2bf(v0.y),f2bf(v0.z),f2bf(v0.w),
                    f2bf(v1.x),f2bf(v1.y),f2bf(v1.z),f2bf(v1.w)};
    *(u16x8*)(Whh_pk + (size_t)base) = *(u16x8*)av;
  } else if (bx < 11928){
    int id = bx - 11520;
    int p = id / 204, tn = id % 204;
    const float* pose = p ? pose2 : pose1;
    float* rawh = rawh_p + p*208896;
    const float* xp = pose + tn*3;             // b=0
    float x0 = xp[0], x1 = xp[1], x2 = xp[2];
    #pragma unroll
    for (int j = 0; j < 4; j++){
      int c = tid + j*256;
      float v = x0*W1[c] + x1*W1[1024+c] + x2*W1[2048+c];
      rh[c] = v;
      rawh[tn*1024 + c] = v;
    }
    __syncthreads();
    int o = tid >> 4, l = tid & 15;
    int h = o & 7;
    const float* av = ((o < 8) ? a_s1 : a_d1) + h*128;
    const float* hv = rh + h*128;
    float s = 0.f;
    #pragma unroll
    for (int q = 0; q < 8; q++) s += hv[l + q*16] * av[l + q*16];
    #pragma unroll
    for (int off = 1; off < 16; off <<= 1) s += __shfl_xor(s, off, 64);
    if (l == 0) ((o < 8) ? al_s_p : al_d_p)[p*2048 + tn*8 + h] = s;
  } else if (bx < 15000){
    int id = bx - 11928;
    int p = id / 1536, bt = id % 1536;
    const float* pose = p ? pose2 : pose1;
    int b = bt/12, t = bt%12;
    if (tid < 38){
      const float* pb = pose + ((b*12 + t)*17)*3;
      int s = d_c0[tid], d = d_c1[tid];
      float vx = pb[d*3+0] - pb[s*3+0];
      float vy = pb[d*3+1] - pb[s*3+1];
      nrm[tid] = sqrtf(vx*vx + vy*vy);
      ang[tid] = atan2f(vy, vx);
    }
    __syncthreads();
    float inv = rsqrtf(bn_v[t] + 1e-5f);
    float sc = inv*bn_g[t], shv = bn_b[t] - bn_m[t]*sc;
    int c = tid & 127, blk = tid >> 7;
    float acc = b_fc[c];
    #pragma unroll
    for (int j = 0; j < 19; j++){
      int e = blk*19 + j;
      acc += nrm[e]*W_fc[(2*j)*128 + c] + ang[e]*W_fc[(2*j+1)*128 + c];
    }
    fb[(((size_t)(p*128+b))*12 + t)*2432 + 2176 + blk*128 + c] = f2bf(acc*sc + shv);
  } else {
    int k = (bx - 15000)*256 + tid;           // 0..1023
    W1e4[k] = make_float4(W1[k], W1[1024+k], W1[2048+k], b1[k]);
  }
}

// ---- D2: gat1_agg (blocks [0,408)) + gat2m (blocks [408,1224)) ----
// gat2m uses single-sync double-buffered LDS and packed W1e4 float4 loads.
#define GLDK 40
__global__ __launch_bounds__(256) void k_front2(
    const float* __restrict__ pose1, const float* __restrict__ pose2,
    const float4* __restrict__ W1e4, const float* __restrict__ b1,
    const ushort* __restrict__ W2mT, const float* __restrict__ b2,
    const float* __restrict__ bn_g, const float* __restrict__ bn_b,
    const float* __restrict__ bn_m, const float* __restrict__ bn_v,
    const float* __restrict__ rawh_p,
    const float* __restrict__ al_s_p, const float* __restrict__ al_d_p,
    ushort* __restrict__ hcat_bf, ushort* __restrict__ fb)
{
  __shared__ ushort As[2][64*GLDK];
  __shared__ ushort Bs[2][128*GLDK];
  __shared__ float sx[64][3];
  int tid = threadIdx.x;
  int bx = blockIdx.x;
  if (bx < 408){
    int p = bx / 204, r = bx % 204;
    const float* rawh = rawh_p + p*208896;
    const float* al_s = al_s_p + p*2048;
    const float* al_d = al_d_p + p*2048;
    int t = r/17, dst = r%17;
    int base = t*17;
    int row = p*204 + base + dst;
    #pragma unroll
    for (int j = 0; j < 4; j++){
      int c = tid + j*256, h = c >> 7;
      float ad = al_d[(base+dst)*8 + h];
      float eself = lrelu02(al_s[(base+dst)*8 + h] + ad);
      float m = eself;
      for (int e = 0; e < 38; e++) if (d_c1[e] == dst)
        m = fmaxf(m, lrelu02(al_s[(base+d_c0[e])*8 + h] + ad));
      float w = __expf(eself - m);
      float den = w;
      float acc = w * rawh[(base+dst)*1024 + c];
      for (int e = 0; e < 38; e++) if (d_c1[e] == dst){
        float v = __expf(lrelu02(al_s[(base+d_c0[e])*8 + h] + ad) - m);
        den += v;
        acc += v * rawh[(base+d_c0[e])*1024 + c];
      }
      float o = acc/den + b1[c];
      hcat_bf[(size_t)row*1024 + c] = f2bf(o > 0.f ? o : __expf(o) - 1.f);
    }
    return;
  }
  int id = bx - 408;
  int n0 = (id % 34) * 64;
  int t  = (id / 34) % 12;
  int p  = id / 408;
  const float* pose = p ? pose2 : pose1;
  if (tid < 192){
    int nd = tid/3, k = tid%3;
    int n = n0+nd, b = n/17, jj = n%17;
    sx[nd][k] = pose[((b*12 + t)*17 + jj)*3 + k];
  }
  __syncthreads();
  float inv = rsqrtf(bn_v[t] + 1e-5f);
  float sc = inv*bn_g[t], shv = bn_b[t] - bn_m[t]*sc;
  int wave = tid >> 6, lane = tid & 63;
  int wm = (wave >> 1)*32, wn = (wave & 1)*64;
  int fr = lane & 15, fg = lane >> 4;
  int and_ = tid >> 2, ak8 = (tid & 3)*8;
  int brow = tid >> 1, bk16 = (tid & 1)*16;
  float ax0 = sx[and_][0], ax1 = sx[and_][1], ax2 = sx[and_][2];

  f32x4 acc[2][4];
  #pragma unroll
  for (int m = 0; m < 2; m++)
    #pragma unroll
    for (int n = 0; n < 4; n++) acc[m][n] = (f32x4){0.f,0.f,0.f,0.f};

  u16x8 vb0 = *(const u16x8*)(W2mT + brow*1024 + bk16);
  u16x8 vb1 = *(const u16x8*)(W2mT + brow*1024 + bk16 + 8);

  for (int k0 = 0; k0 < 1024; k0 += 32){
    int cb = (k0 >> 5) & 1;
    ushort av[8];
    #pragma unroll
    for (int q = 0; q < 8; q++){
      float4 w = W1e4[k0 + ak8 + q];
      float hv = ax0*w.x + ax1*w.y + ax2*w.z + w.w;
      hv = hv > 0.f ? hv : __expf(hv) - 1.f;
      av[q] = f2bf(hv);
    }
    *(u16x8*)(&As[cb][and_*GLDK + ak8]) = *(u16x8*)av;
    *(u16x8*)(&Bs[cb][brow*GLDK + bk16])     = vb0;
    *(u16x8*)(&Bs[cb][brow*GLDK + bk16 + 8]) = vb1;
    __syncthreads();
    if (k0 + 32 < 1024){
      vb0 = *(const u16x8*)(W2mT + brow*1024 + k0 + 32 + bk16);
      vb1 = *(const u16x8*)(W2mT + brow*1024 + k0 + 32 + bk16 + 8);
    }
    bf16x8 af[2], bfv[4];
    #pragma unroll
    for (int m = 0; m < 2; m++)
      af[m] = *(const bf16x8*)(&As[cb][(wm + m*16 + fr)*GLDK + fg*8]);
    #pragma unroll
    for (int n = 0; n < 4; n++)
      bfv[n] = *(const bf16x8*)(&Bs[cb][(wn + n*16 + fr)*GLDK + fg*8]);
    #pragma unroll
    for (int m = 0; m < 2; m++)
      #pragma unroll
      for (int n = 0; n < 4; n++)
        acc[m][n] = __builtin_amdgcn_mfma_f32_16x16x32_bf16(af[m], bfv[n], acc[m][n], 0, 0, 0);
  }

  #pragma unroll
  for (int m = 0; m < 2; m++){
    #pragma unroll
    for (int n = 0; n < 4; n++){
      int col = wn + n*16 + fr;
      float bb = b2[col];
      #pragma unroll
      for (int j = 0; j < 4; j++){
        int node = n0 + wm + m*16 + fg*4 + j;
        int b = node/17, jj = node%17;
        float val = (acc[m][n][j] + bb)*sc + shv;
        fb[(((size_t)(p*128+b))*12 + t)*2432 + jj*128 + col] = f2bf(val);
      }
    }
  }
}

// h2s = hcat_bf @ W2tb^T; BM=32 tiles (grid 8x13), single-sync dbuf LDS;
// al2 epilogue per head-block.
#define PLDK 40
__global__ __launch_bounds__(256) void k_gat2sp(
    const ushort* __restrict__ hcat_bf,   // [448][1024] (rows >=408 garbage)
    const ushort* __restrict__ W2tb,      // [1024][1024]
    const float* __restrict__ a_s, const float* __restrict__ a_d,
    float* __restrict__ h2s,              // [408][1024]
    float* __restrict__ al_s_p, float* __restrict__ al_d_p)
{
  __shared__ ushort As[2][32*PLDK];
  __shared__ ushort Bs[2][128*PLDK];
  __shared__ float alred[32][2][2];
  int tid = threadIdx.x;
  int bm = blockIdx.y * 32;
  int bn = blockIdx.x * 128;
  int hh = blockIdx.x;
  int wave = tid >> 6, lane = tid & 63;
  int wm = (wave >> 1)*16, wn = (wave & 1)*64;
  int fr = lane & 15, fg = lane >> 4;
  int arow = tid >> 2, ak8 = (tid & 3)*8;     // A staging: tid<128 only
  int brow = tid >> 1, bk16 = (tid & 1)*16;

  f32x4 acc[4];
  #pragma unroll
  for (int n = 0; n < 4; n++) acc[n] = (f32x4){0.f,0.f,0.f,0.f};

  const ushort* ga = hcat_bf + (size_t)(bm+arow)*1024 + ak8;   // rows <448 safe
  const ushort* gb = W2tb + (size_t)(bn+brow)*1024 + bk16;
  u16x8 va  = *(const u16x8*)ga;
  u16x8 vb0 = *(const u16x8*)gb;
  u16x8 vb1 = *(const u16x8*)(gb + 8);

  for (int k0 = 0; k0 < 1024; k0 += 32){
    int cb = (k0 >> 5) & 1;
    if (tid < 128) *(u16x8*)(&As[cb][arow*PLDK + ak8]) = va;
    *(u16x8*)(&Bs[cb][brow*PLDK + bk16])     = vb0;
    *(u16x8*)(&Bs[cb][brow*PLDK + bk16 + 8]) = vb1;
    __syncthreads();
    if (k0 + 32 < 1024){
      va  = *(const u16x8*)(ga + k0 + 32);
      vb0 = *(const u16x8*)(gb + k0 + 32);
      vb1 = *(const u16x8*)(gb + k0 + 40);
    }
    bf16x8 af = *(const bf16x8*)(&As[cb][(wm + fr)*PLDK + fg*8]);
    bf16x8 bfv[4];
    #pragma unroll
    for (int n = 0; n < 4; n++)
      bfv[n] = *(const bf16x8*)(&Bs[cb][(wn + n*16 + fr)*PLDK + fg*8]);
    #pragma unroll
    for (int n = 0; n < 4; n++)
      acc[n] = __builtin_amdgcn_mfma_f32_16x16x32_bf16(af, bfv[n], acc[n], 0, 0, 0);
  }

  #pragma unroll
  for (int n = 0; n < 4; n++){
    int col = bn + wn + n*16 + fr;
    #pragma unroll
    for (int j = 0; j < 4; j++){
      int row = bm + wm + fg*4 + j;
      if (row < 408) h2s[(size_t)row*1024 + col] = acc[n][j];
    }
  }

  // ---- al2 epilogue (head hh complete in this block) ----
  float avs[4], avd[4];
  #pragma unroll
  for (int n = 0; n < 4; n++){
    avs[n] = a_s[hh*128 + wn + n*16 + fr];
    avd[n] = a_d[hh*128 + wn + n*16 + fr];
  }
  #pragma unroll
  for (int j = 0; j < 4; j++){
    float ps = 0.f, pd = 0.f;
    #pragma unroll
    for (int n = 0; n < 4; n++){
      ps += acc[n][j]*avs[n];
      pd += acc[n][j]*avd[n];
    }
    #pragma unroll
    for (int off = 1; off < 16; off <<= 1){
      ps += __shfl_xor(ps, off, 64);
      pd += __shfl_xor(pd, off, 64);
    }
    if (fr == 0){
      int rl = wm + fg*4 + j;
      alred[rl][wave & 1][0] = ps;
      alred[rl][wave & 1][1] = pd;
    }
  }
  __syncthreads();
  if (tid < 64){
    int rl = tid & 31, kind = tid >> 5;
    int grow = bm + rl;
    if (grow < 408){
      float v = alred[rl][0][kind] + alred[rl][1][kind];
      int p = grow / 204, tn = grow % 204;
      (kind ? al_d_p : al_s_p)[p*2048 + tn*8 + hh] = v;
    }
  }
}

// layer-2 aggregation + head mean + BN + bf16 write (overwrites fb rows of b=0)
__global__ void k_gat2_agg(const float* __restrict__ h2s_p, const float* __restrict__ al_s_p,
    const float* __restrict__ al_d_p, const float* __restrict__ b2,
    const float* __restrict__ bn_g, const float* __restrict__ bn_b,
    const float* __restrict__ bn_m, const float* __restrict__ bn_v,
    ushort* __restrict__ fb){
  int p = blockIdx.x / 204, r = blockIdx.x % 204;
  const float* h2s = h2s_p + p*208896;
  const float* al_s = al_s_p + p*2048;
  const float* al_d = al_d_p + p*2048;
  int t = r/17, dst = r%17;
  int base = t*17, c = threadIdx.x;             // 128 threads
  float sum = 0.f;
  for (int h = 0; h < 8; h++){
    float ad = al_d[(base+dst)*8 + h];
    float eself = lrelu02(al_s[(base+dst)*8 + h] + ad);
    float m = eself;
    for (int e = 0; e < 38; e++) if (d_c1[e] == dst)
      m = fmaxf(m, lrelu02(al_s[(base+d_c0[e])*8 + h] + ad));
    float w = __expf(eself - m), den = w;
    float acc = w * h2s[(base+dst)*1024 + h*128 + c];
    for (int e = 0; e < 38; e++) if (d_c1[e] == dst){
      float v = __expf(lrelu02(al_s[(base+d_c0[e])*8 + h] + ad) - m);
      den += v;
      acc += v * h2s[(base+d_c0[e])*1024 + h*128 + c];
    }
    sum += acc/den;
  }
  float inv = rsqrtf(bn_v[t] + 1e-5f);
  float sc = inv*bn_g[t], shv = bn_b[t] - bn_m[t]*sc;
  float val = (sum*0.125f + b2[c])*sc + shv;
  fb[(((size_t)(p*128))*12 + t)*2432 + dst*128 + c] = f2bf(val);
}

// bf16 MFMA projection GEMM with global_load_lds staging; bf16 output (pre_bf)
__global__ __launch_bounds__(256) void k_proj_mfma(
    const ushort* __restrict__ Abf,   // [3072][2432]
    const ushort* __restrict__ Wbf,   // [2][2048][2432]
    const float* __restrict__ bih_f, const float* __restrict__ bhh_f,
    const float* __restrict__ bih_b, const float* __restrict__ bhh_b,
    ushort* __restrict__ pre_bf)
{
  __shared__ ushort As[128*32];       // linear [row][k], 64 B rows
  __shared__ ushort Bs[128*32];
  int tid = threadIdx.x;
  int bm = blockIdx.y * 128;
  int dir = blockIdx.x >> 4;
  int bn = (blockIdx.x & 15) * 128;
  const ushort* W = Wbf + (size_t)dir * (2048*2432);
  const float* bi = dir ? bih_b : bih_f;
  const float* bh = dir ? bhh_b : bhh_f;
  ushort* C = pre_bf + (size_t)dir * 6291456;

  int wave = tid >> 6, lane = tid & 63;
  int wm = (wave >> 1) * 64, wn = (wave & 1) * 64;
  int fr = lane & 15, fg = lane >> 4;

  int grow = tid >> 2, gks = (tid & 3) * 8;
  const ushort* gaBase = Abf + (size_t)(bm + grow)*2432 + gks;
  const ushort* gbBase = W   + (size_t)(bn + grow)*2432 + gks;
  ushort* ldsA0 = &As[(wave*16)*32];
  ushort* ldsA1 = &As[(64 + wave*16)*32];
  ushort* ldsB0 = &Bs[(wave*16)*32];
  ushort* ldsB1 = &Bs[(64 + wave*16)*32];

  f32x4 acc[4][4];
  #pragma unroll
  for (int i = 0; i < 4; i++)
    #pragma unroll
    for (int j = 0; j < 4; j++) acc[i][j] = (f32x4){0.f,0.f,0.f,0.f};

  for (int k0 = 0; k0 < 2432; k0 += 32){
    __syncthreads();
    llds16(gaBase + k0,             ldsA0);
    llds16(gaBase + k0 + 64*2432,   ldsA1);
    llds16(gbBase + k0,             ldsB0);
    llds16(gbBase + k0 + 64*2432,   ldsB1);
    __syncthreads();
    bf16x8 af[4], bfv[4];
    #pragma unroll
    for (int m = 0; m < 4; m++)
      af[m] = *(const bf16x8*)(&As[(wm + m*16 + fr)*32 + fg*8]);
    #pragma unroll
    for (int n = 0; n < 4; n++)
      bfv[n] = *(const bf16x8*)(&Bs[(wn + n*16 + fr)*32 + fg*8]);
    #pragma unroll
    for (int m = 0; m < 4; m++)
      #pragma unroll
      for (int n = 0; n < 4; n++)
        acc[m][n] = __builtin_amdgcn_mfma_f32_16x16x32_bf16(af[m], bfv[n], acc[m][n], 0, 0, 0);
  }

  #pragma unroll
  for (int m = 0; m < 4; m++){
    #pragma unroll
    for (int n = 0; n < 4; n++){
      int col = bn + wn + n*16 + fr;
      float bsum = bi[col] + bh[col];
      #pragma unroll
      for (int j = 0; j < 4; j++){
        int row = bm + wm + m*16 + fg*4 + j;
        C[(size_t)row*2048 + col] = f2bf(acc[m][n][j] + bsum);
      }
    }
  }
}

// fused LSTM step: 512 threads / 8 waves; waves split K into two halves.
__global__ __launch_bounds__(512) void k_lstm_step(
    ushort* __restrict__ hbf, const ushort* __restrict__ Whh_pk,
    const ushort* __restrict__ pre_bf, float* __restrict__ cbuf,
    float* __restrict__ lout, int s)
{
  int dir = blockIdx.z;
  int bm = blockIdx.y * 64;
  int bn = blockIdx.x * 64;
  int tCur = dir ? (11 - s) : s;
  int tid = threadIdx.x, wave = tid >> 6, lane = tid & 63;
  int kg = wave >> 2, wv = wave & 3;
  int fr = lane & 15, fg = lane >> 4;
  __shared__ ushort As[2][64*32];
  __shared__ float sg[64][68];
  f32x4 acc[4];
  #pragma unroll
  for (int n = 0; n < 4; n++) acc[n] = (f32x4){0.f,0.f,0.f,0.f};

  if (s > 0){
    const ushort* hA = hbf + ((size_t)((s&1)*2 + dir))*131072;
    int rsub = lane >> 2, kl = (lane & 3)*8;
    const ushort* gA = hA + (size_t)(bm + wv*16 + rsub)*512 + kg*256 + kl;
    ushort* lA = &As[kg][(wv*16)*32];
    const ushort* wb = Whh_pk + (size_t)dir*1048576
                     + (size_t)blockIdx.x*32768 + kg*16384 + lane*8;
    bf16x8 nb0 = *(const bf16x8*)(wb);
    bf16x8 nb1 = *(const bf16x8*)(wb + 512);
    bf16x8 nb2 = *(const bf16x8*)(wb + 1024);
    bf16x8 nb3 = *(const bf16x8*)(wb + 1536);
    #pragma unroll
    for (int kk = 0; kk < 8; kk++){
      __builtin_amdgcn_sched_barrier(0);
      llds16(gA + kk*32, lA);
      bf16x8 b0 = nb0, b1 = nb1, b2 = nb2, b3 = nb3;
      if (kk < 7){
        nb0 = *(const bf16x8*)(wb + (kk+1)*2048);
        nb1 = *(const bf16x8*)(wb + (kk+1)*2048 + 512);
        nb2 = *(const bf16x8*)(wb + (kk+1)*2048 + 1024);
        nb3 = *(const bf16x8*)(wb + (kk+1)*2048 + 1536);
      }
      __syncthreads();
      bf16x8 af = *(const bf16x8*)(&As[kg][(wv*16 + fr)*32 + fg*8]);
      acc[0] = __builtin_amdgcn_mfma_f32_16x16x32_bf16(af, b0, acc[0], 0, 0, 0);
      acc[1] = __builtin_amdgcn_mfma_f32_16x16x32_bf16(af, b1, acc[1], 0, 0, 0);
      acc[2] = __builtin_amdgcn_mfma_f32_16x16x32_bf16(af, b2, acc[2], 0, 0, 0);
      acc[3] = __builtin_amdgcn_mfma_f32_16x16x32_bf16(af, b3, acc[3], 0, 0, 0);
    }
    __syncthreads();
  }
  if (kg == 0){
    #pragma unroll
    for (int n = 0; n < 4; n++)
      #pragma unroll
      for (int j = 0; j < 4; j++)
        sg[wv*16 + fg*4 + j][n*16 + fr] = acc[n][j];
  }
  __syncthreads();
  if (kg == 1){
    #pragma unroll
    for (int n = 0; n < 4; n++)
      #pragma unroll
      for (int j = 0; j < 4; j++)
        sg[wv*16 + fg*4 + j][n*16 + fr] += acc[n][j];
  }
  __syncthreads();

  int ul = tid & 15, rb = tid >> 4;
  int u = (bn >> 2) + ul;
  ushort* hw = hbf + ((size_t)(((s&1)^1)*2 + dir))*131072;
  #pragma unroll
  for (int q = 0; q < 2; q++){
    int r = rb + q*32, b = bm + r;
    const ushort* pb = pre_bf + (size_t)dir*6291456 + ((size_t)b*12 + tCur)*2048;
    float gi = sg[r][ul*4+0] + bf2f(pb[u]);
    float gf = sg[r][ul*4+1] + bf2f(pb[512+u]);
    float gg = sg[r][ul*4+2] + bf2f(pb[1024+u]);
    float go = sg[r][ul*4+3] + bf2f(pb[1536+u]);
    float cP = (s > 0) ? cbuf[dir*131072 + b*512 + u] : 0.f;
    float cN = sigmoidf_(gf)*cP + sigmoidf_(gi)*tanhf(gg);
    float h = sigmoidf_(go)*tanhf(cN);
    cbuf[dir*131072 + b*512 + u] = cN;
    lout[((size_t)b*12 + tCur)*1024 + dir*512 + u] = h;
    hw[(size_t)b*512 + u] = f2bf(h);
  }
}

// fp32 GEMM, 32x32 tiles: C[M,N] = A[M,K] @ B[N,K]^T (+bias)
__global__ __launch_bounds__(256) void k_gemm32(
    const float* __restrict__ A, int lda,
    const float* __restrict__ B, int ldb,
    float* __restrict__ C, int ldc,
    int M, int N, int K,
    const float* __restrict__ bias1)
{
  __shared__ float As[16][36];
  __shared__ float Bs[16][36];
  int tid = threadIdx.x;
  int bm = blockIdx.y*32, bn = blockIdx.x*32;
  int half = tid >> 7, t = tid & 127;
  int lr = t >> 2, lkq = (t & 3) * 4;
  int tx = tid & 15, ty = tid >> 4;
  float acc[2][2] = {{0.f,0.f},{0.f,0.f}};
  for (int k0 = 0; k0 < K; k0 += 16){
    float4 v = make_float4(0.f,0.f,0.f,0.f);
    if (half == 0){ int r = bm + lr; if (r < M) v = *(const float4*)(A + (size_t)r*lda + k0 + lkq); }
    else          { int r = bn + lr; if (r < N) v = *(const float4*)(B + (size_t)r*ldb + k0 + lkq); }
    if (k0) __syncthreads();
    if (half == 0){ As[lkq+0][lr]=v.x; As[lkq+1][lr]=v.y; As[lkq+2][lr]=v.z; As[lkq+3][lr]=v.w; }
    else          { Bs[lkq+0][lr]=v.x; Bs[lkq+1][lr]=v.y; Bs[lkq+2][lr]=v.z; Bs[lkq+3][lr]=v.w; }
    __syncthreads();
    #pragma unroll
    for (int kk = 0; kk < 16; kk++){
      float a0 = As[kk][ty*2], a1 = As[kk][ty*2+1];
      float b0 = Bs[kk][tx*2], b1 = Bs[kk][tx*2+1];
      acc[0][0] += a0*b0; acc[0][1] += a0*b1;
      acc[1][0] += a1*b0; acc[1][1] += a1*b1;
    }
  }
  #pragma unroll
  for (int i = 0; i < 2; i++){
    int r = bm + ty*2 + i;
    if (r >= M) continue;
    #pragma unroll
    for (int j = 0; j < 2; j++){
      int cc = bn + tx*2 + j;
      if (cc >= N) continue;
      float v = acc[i][j];
      if (bias1) v += bias1[cc];
      C[(size_t)r*ldc + cc] = v;
    }
  }
}

// temporal attention pool
__global__ __launch_bounds__(256) void k_attention(const float* __restrict__ lout,
    const float* __restrict__ W_att, float* __restrict__ attended){
  int b = blockIdx.x, tid = threadIdx.x;
  __shared__ float part[256*12];
  __shared__ float sc[12];
  float p[12];
  #pragma unroll
  for (int t = 0; t < 12; t++) p[t] = 0.f;
  #pragma unroll
  for (int j = 0; j < 4; j++){
    int c = tid + j*256;
    float w = W_att[c];
    #pragma unroll
    for (int t = 0; t < 12; t++) p[t] += lout[((size_t)b*12 + t)*1024 + c] * w;
  }
  #pragma unroll
  for (int t = 0; t < 12; t++) part[tid*12 + t] = p[t];
  __syncthreads();
  if (tid < 12){
    float s = 0.f;
    for (int i = 0; i < 256; i++) s += part[i*12 + tid];
    sc[tid] = s;
  }
  __syncthreads();
  float m = sc[0];
  #pragma unroll
  for (int t = 1; t < 12; t++) m = fmaxf(m, sc[t]);
  float wt[12], den = 0.f;
  #pragma unroll
  for (int t = 0; t < 12; t++){ wt[t] = __expf(sc[t] - m); den += wt[t]; }
  float inv = 1.f/den;
  #pragma unroll
  for (int j = 0; j < 4; j++){
    int c = tid + j*256;
    float a = 0.f;
    #pragma unroll
    for (int t = 0; t < 12; t++) a += wt[t]*lout[((size_t)b*12 + t)*1024 + c];
    attended[(size_t)b*1024 + c] = a*inv;
  }
}

extern "C" void kernel_launch(void* const* d_in, const int* in_sizes, int n_in,
                              void* d_out, int out_size, void* d_ws, size_t ws_size,
                              hipStream_t stream)
{
  const float* pose1 = (const float*)d_in[0];
  const float* pose2 = (const float*)d_in[1];
  const float* W1    = (const float*)d_in[2];
  const float* a_src1= (const float*)d_in[3];
  const float* a_dst1= (const float*)d_in[4];
  const float* b1    = (const float*)d_in[5];
  const float* W2    = (const float*)d_in[6];
  const float* a_src2= (const float*)d_in[7];
  const float* a_dst2= (const float*)d_in[8];
  const float* b2    = (const float*)d_in[9];
  const float* W_fc  = (const float*)d_in[10];
  const float* b_fc  = (const float*)d_in[11];
  const float* bn_g  = (const float*)d_in[12];
  const float* bn_b  = (const float*)d_in[13];
  const float* bn_m  = (const float*)d_in[14];
  const float* bn_v  = (const float*)d_in[15];
  const float* Wih_f = (const float*)d_in[16];
  const float* Whh_f = (const float*)d_in[17];
  const float* bih_f = (const float*)d_in[18];
  const float* bhh_f = (const float*)d_in[19];
  const float* Wih_b = (const float*)d_in[20];
  const float* Whh_b = (const float*)d_in[21];
  const float* bih_b = (const float*)d_in[22];
  const float* bhh_b = (const float*)d_in[23];
  const float* W_att = (const float*)d_in[24];
  const float* W_cls = (const float*)d_in[26];
  const float* b_cls = (const float*)d_in[27];
  (void)in_sizes; (void)n_in; (void)out_size; (void)ws_size;

  float* ws = (float*)d_ws;
  // weight region (7,471,104 f), written once by k_front1:
  ushort* Wbf     = (ushort*)ws;                     // 9,961,472 u
  ushort* Whh_pk  = (ushort*)(ws + 4980736);         // 2,097,152 u (fragment-packed)
  ushort* W2tb    = (ushort*)(ws + 6029312);         // 1,048,576 u
  ushort* W2mT    = (ushort*)(ws + 6553600);         // 131,072 u
  float4* W1e4    = (float4*)(ws + 6619136);         // 1024 float4 (4096 f)
  ushort* pre_bf  = (ushort*)(ws + 7471104);         // [2][3072][2048] u
  float* rawh_p   = ws + 7471104;                    // 2x208,896 f (dead before proj)
  float* R        = ws + 20054016;                   // phase-multiplexed
  // GAT phase in R:
  ushort* fb      = (ushort*)R;                      // [3072][2432] bf16
  float* h2s      = R + 3735552;                     // [408][1024] f
  ushort* hcat_bf = (ushort*)(R + 4153344);          // [448][1024] u
  float* alB      = R + 4382720;                     // 16,384 f
  float* al1s = alB, *al1d = alB + 4096, *al2s = alB + 8192, *al2d = alB + 12288;
  // LSTM phase in R (fb dead after proj):
  ushort* hbf = (ushort*)R;
  float* cbuf = R + 262144;
  float* lout = R + 524288;

  float* attended = (float*)d_out;                   // [256][1024]
  float* logits   = attended + 262144;               // [256][500]

  k_front1<<<15004, 256, 0, stream>>>(W2, Wih_f, Wih_b, Whh_f, Whh_b,
      pose1, pose2, W1, b1, a_src1, a_dst1, W_fc, b_fc,
      bn_g, bn_b, bn_m, bn_v,
      W2mT, W2tb, Wbf, Whh_pk, rawh_p, al1s, al1d, fb, W1e4);

  k_front2<<<1224, 256, 0, stream>>>(pose1, pose2, W1e4, b1, W2mT, b2,
      bn_g, bn_b, bn_m, bn_v, rawh_p, al1s, al1d, hcat_bf, fb);

  k_gat2sp<<<dim3(8,13), 256, 0, stream>>>(hcat_bf, W2tb, a_src2, a_dst2,
                                           h2s, al2s, al2d);
  k_gat2_agg<<<408, 128, 0, stream>>>(h2s, al2s, al2d, b2,
                                      bn_g, bn_b, bn_m, bn_v, fb);

  k_proj_mfma<<<dim3(32, 24), 256, 0, stream>>>(fb, Wbf,
      bih_f, bhh_f, bih_b, bhh_b, pre_bf);

  for (int s = 0; s < 12; s++)
    k_lstm_step<<<dim3(32,4,2), 512, 0, stream>>>(hbf, Whh_pk, pre_bf, cbuf, lout, s);

  k_attention<<<256, 256, 0, stream>>>(lout, W_att, attended);
  k_gemm32<<<dim3(16,8), 256, 0, stream>>>(attended, 1024, W_cls, 1024, logits, 500,
                                           256, 500, 1024, b_cls);
}

// Round 17
// 352.038 us; speedup vs baseline: 1.2338x; 1.2338x over previous
//
#include <hip/hip_runtime.h>
#include <hip/hip_bf16.h>
#include <math.h>

// Sizes
#define B_    128
#define T_    12
#define J_    17
#define HID_  128
#define LH_   512
#define NC_   500

typedef short  bf16x8 __attribute__((ext_vector_type(8)));
typedef ushort u16x8  __attribute__((ext_vector_type(8)));
typedef float  f32x4  __attribute__((ext_vector_type(4)));

__constant__ int d_c0[38] = {15,13,16,14,11,5,6,5,5,6,7,8,1,0,0,1,2,3,4,
                             13,11,14,12,12,11,12,6,7,8,9,10,2,1,2,3,4,5,6};
__constant__ int d_c1[38] = {13,11,14,12,12,11,12,6,7,8,9,10,2,1,2,3,4,5,6,
                             15,13,16,14,11,5,6,5,5,6,7,8,1,0,0,1,2,3,4};

__device__ __forceinline__ float lrelu02(float x){ return x > 0.f ? x : 0.2f*x; }
__device__ __forceinline__ float sigmoidf_(float x){ return 1.f/(1.f+__expf(-x)); }
__device__ __forceinline__ ushort f2bf(float f){
  uint32_t u = __builtin_bit_cast(uint32_t, f);
  uint32_t r = (u + 0x7fffu + ((u >> 16) & 1u)) >> 16;
  return (ushort)r;
}
__device__ __forceinline__ float bf2f(ushort u){
  uint32_t v = ((uint32_t)u) << 16;
  return __builtin_bit_cast(float, v);
}
// async global->LDS, 16B per lane; LDS dest wave-uniform base (+lane*16 implicit)
__device__ __forceinline__ void llds16(const ushort* g, ushort* l){
  __builtin_amdgcn_global_load_lds(
      (const __attribute__((address_space(1))) void*)g,
      (__attribute__((address_space(3))) void*)l,
      16, 0, 0);
}

// ---- D1: independent front-end work in ONE dispatch ----
//   [0,512)         W2mT[c][k] = bf16((1/8) sum_h W2[k][h*128+c])
//   [512,768)       W2tb[n][k] = bf16(W2[k][n])
//   [768,10496)     Wih f+b -> bf16 concat
//   [10496,11520)   Whh gate-permuted, MFMA-fragment-packed bf16
//   [11520,11928)   gat1s_al: rawh row + al1 logits
//   [11928,15000)   edge branch + BN + bf16 -> fb
__global__ __launch_bounds__(256) void k_front1(const float* __restrict__ W2,
    const float* __restrict__ Wih_f, const float* __restrict__ Wih_b,
    const float* __restrict__ Whh_f, const float* __restrict__ Whh_b,
    const float* __restrict__ pose1, const float* __restrict__ pose2,
    const float* __restrict__ W1,
    const float* __restrict__ a_s1, const float* __restrict__ a_d1,
    const float* __restrict__ W_fc, const float* __restrict__ b_fc,
    const float* __restrict__ bn_g, const float* __restrict__ bn_b,
    const float* __restrict__ bn_m, const float* __restrict__ bn_v,
    ushort* __restrict__ W2mT, ushort* __restrict__ W2tb,
    ushort* __restrict__ Wbf, ushort* __restrict__ Whh_pk,
    float* __restrict__ rawh_p, float* __restrict__ al_s_p, float* __restrict__ al_d_p,
    ushort* __restrict__ fb)
{
  __shared__ ushort sh[64][68];
  __shared__ float rh[1024];
  __shared__ float nrm[38], ang[38];
  int tid = threadIdx.x;
  int bx = blockIdx.x;
  if (bx < 512){
    int idx = bx*256 + tid;
    int c = idx >> 10, k = idx & 1023;
    float s = 0.f;
    #pragma unroll
    for (int h = 0; h < 8; h++) s += W2[k*1024 + h*128 + c];
    W2mT[idx] = f2bf(s * 0.125f);
  } else if (bx < 768){
    int b2x = bx - 512;
    int k0 = (b2x >> 4)*64, n0 = (b2x & 15)*64;
    #pragma unroll
    for (int q = 0; q < 16; q++){
      int idx = tid + q*256;
      int kk = idx >> 6, nn = idx & 63;
      sh[nn][kk] = f2bf(W2[(size_t)(k0+kk)*1024 + n0+nn]);
    }
    __syncthreads();
    #pragma unroll
    for (int q = 0; q < 16; q++){
      int idx = tid + q*256;
      int nn = idx >> 6, kk = idx & 63;
      W2tb[(size_t)(n0+nn)*1024 + k0+kk] = sh[nn][kk];
    }
  } else if (bx < 10496){
    const int S = 2048*2432;
    int i4 = (bx - 768)*256 + tid;
    int idx = i4*4;
    if (idx >= 2*S) return;
    const float* src = (idx < S) ? (Wih_f + idx) : (Wih_b + (idx - S));
    float4 v = *(const float4*)src;
    ushort4 o;
    o.x = f2bf(v.x); o.y = f2bf(v.y); o.z = f2bf(v.z); o.w = f2bf(v.w);
    *(ushort4*)(Wbf + idx) = o;
  } else if (bx < 11520){
    int i = (bx - 10496)*256 + tid;
    int base = i*8;
    int dir = base >> 20;
    int idx8 = (base & 1048575) >> 3;
    int lane = idx8 & 63;
    int t1 = idx8 >> 6;
    int n  = t1 & 3;
    int t2 = t1 >> 2;
    int kk = t2 & 7;
    int t3 = t2 >> 3;
    int kg = t3 & 1;
    int nb = t3 >> 1;
    int col = nb*64 + n*16 + (lane & 15);
    int u = col >> 2, g = col & 3;
    int k = kg*256 + kk*32 + (lane >> 4)*8;
    const float* src = (dir ? Whh_b : Whh_f) + ((size_t)(g*512+u))*512 + k;
    float4 v0 = *(const float4*)src;
    float4 v1 = *(const float4*)(src+4);
    ushort av[8] = {f2bf(v0.x),f2bf(v0.y),f2bf(v0.z),f2bf(v0.w),
                    f2bf(v1.x),f2bf(v1.y),f2bf(v1.z),f2bf(v1.w)};
    *(u16x8*)(Whh_pk + (size_t)base) = *(u16x8*)av;
  } else if (bx < 11928){
    int id = bx - 11520;
    int p = id / 204, tn = id % 204;
    const float* pose = p ? pose2 : pose1;
    float* rawh = rawh_p + p*208896;
    const float* xp = pose + tn*3;             // b=0
    float x0 = xp[0], x1 = xp[1], x2 = xp[2];
    #pragma unroll
    for (int j = 0; j < 4; j++){
      int c = tid + j*256;
      float v = x0*W1[c] + x1*W1[1024+c] + x2*W1[2048+c];
      rh[c] = v;
      rawh[tn*1024 + c] = v;
    }
    __syncthreads();
    int o = tid >> 4, l = tid & 15;
    int h = o & 7;
    const float* av = ((o < 8) ? a_s1 : a_d1) + h*128;
    const float* hv = rh + h*128;
    float s = 0.f;
    #pragma unroll
    for (int q = 0; q < 8; q++) s += hv[l + q*16] * av[l + q*16];
    #pragma unroll
    for (int off = 1; off < 16; off <<= 1) s += __shfl_xor(s, off, 64);
    if (l == 0) ((o < 8) ? al_s_p : al_d_p)[p*2048 + tn*8 + h] = s;
  } else {
    int id = bx - 11928;
    int p = id / 1536, bt = id % 1536;
    const float* pose = p ? pose2 : pose1;
    int b = bt/12, t = bt%12;
    if (tid < 38){
      const float* pb = pose + ((b*12 + t)*17)*3;
      int s = d_c0[tid], d = d_c1[tid];
      float vx = pb[d*3+0] - pb[s*3+0];
      float vy = pb[d*3+1] - pb[s*3+1];
      nrm[tid] = sqrtf(vx*vx + vy*vy);
      ang[tid] = atan2f(vy, vx);
    }
    __syncthreads();
    float inv = rsqrtf(bn_v[t] + 1e-5f);
    float sc = inv*bn_g[t], shv = bn_b[t] - bn_m[t]*sc;
    int c = tid & 127, blk = tid >> 7;
    float acc = b_fc[c];
    #pragma unroll
    for (int j = 0; j < 19; j++){
      int e = blk*19 + j;
      acc += nrm[e]*W_fc[(2*j)*128 + c] + ang[e]*W_fc[(2*j+1)*128 + c];
    }
    fb[(((size_t)(p*128+b))*12 + t)*2432 + 2176 + blk*128 + c] = f2bf(acc*sc + shv);
  }
}

// ---- D2: gat1_agg (blocks [0,408)) + gat2m (blocks [408,1224)) ----
#define GLDK 40
__global__ __launch_bounds__(256) void k_front2(
    const float* __restrict__ pose1, const float* __restrict__ pose2,
    const float* __restrict__ W1, const float* __restrict__ b1,
    const ushort* __restrict__ W2mT, const float* __restrict__ b2,
    const float* __restrict__ bn_g, const float* __restrict__ bn_b,
    const float* __restrict__ bn_m, const float* __restrict__ bn_v,
    const float* __restrict__ rawh_p,
    const float* __restrict__ al_s_p, const float* __restrict__ al_d_p,
    ushort* __restrict__ hcat_bf, ushort* __restrict__ fb)
{
  __shared__ ushort As[64*GLDK];
  __shared__ ushort Bs[128*GLDK];
  __shared__ float sx[64][3];
  int tid = threadIdx.x;
  int bx = blockIdx.x;
  if (bx < 408){
    int p = bx / 204, r = bx % 204;
    const float* rawh = rawh_p + p*208896;
    const float* al_s = al_s_p + p*2048;
    const float* al_d = al_d_p + p*2048;
    int t = r/17, dst = r%17;
    int base = t*17;
    int row = p*204 + base + dst;
    #pragma unroll
    for (int j = 0; j < 4; j++){
      int c = tid + j*256, h = c >> 7;
      float ad = al_d[(base+dst)*8 + h];
      float eself = lrelu02(al_s[(base+dst)*8 + h] + ad);
      float m = eself;
      for (int e = 0; e < 38; e++) if (d_c1[e] == dst)
        m = fmaxf(m, lrelu02(al_s[(base+d_c0[e])*8 + h] + ad));
      float w = __expf(eself - m);
      float den = w;
      float acc = w * rawh[(base+dst)*1024 + c];
      for (int e = 0; e < 38; e++) if (d_c1[e] == dst){
        float v = __expf(lrelu02(al_s[(base+d_c0[e])*8 + h] + ad) - m);
        den += v;
        acc += v * rawh[(base+d_c0[e])*1024 + c];
      }
      float o = acc/den + b1[c];
      hcat_bf[(size_t)row*1024 + c] = f2bf(o > 0.f ? o : __expf(o) - 1.f);
    }
    return;
  }
  int id = bx - 408;
  int n0 = (id % 34) * 64;
  int t  = (id / 34) % 12;
  int p  = id / 408;
  const float* pose = p ? pose2 : pose1;
  if (tid < 192){
    int nd = tid/3, k = tid%3;
    int n = n0+nd, b = n/17, jj = n%17;
    sx[nd][k] = pose[((b*12 + t)*17 + jj)*3 + k];
  }
  __syncthreads();
  float inv = rsqrtf(bn_v[t] + 1e-5f);
  float sc = inv*bn_g[t], shv = bn_b[t] - bn_m[t]*sc;
  int wave = tid >> 6, lane = tid & 63;
  int wm = (wave >> 1)*32, wn = (wave & 1)*64;
  int fr = lane & 15, fg = lane >> 4;
  int and_ = tid >> 2, ak8 = (tid & 3)*8;
  int brow = tid >> 1, bk16 = (tid & 1)*16;
  float ax0 = sx[and_][0], ax1 = sx[and_][1], ax2 = sx[and_][2];

  f32x4 acc[2][4];
  #pragma unroll
  for (int m = 0; m < 2; m++)
    #pragma unroll
    for (int n = 0; n < 4; n++) acc[m][n] = (f32x4){0.f,0.f,0.f,0.f};

  u16x8 vb0 = *(const u16x8*)(W2mT + brow*1024 + bk16);
  u16x8 vb1 = *(const u16x8*)(W2mT + brow*1024 + bk16 + 8);

  for (int k0 = 0; k0 < 1024; k0 += 32){
    ushort av[8];
    #pragma unroll
    for (int q = 0; q < 8; q++){
      int k = k0 + ak8 + q;
      float hv = ax0*W1[k] + ax1*W1[1024+k] + ax2*W1[2048+k] + b1[k];
      hv = hv > 0.f ? hv : __expf(hv) - 1.f;
      av[q] = f2bf(hv);
    }
    if (k0) __syncthreads();
    *(u16x8*)(&As[and_*GLDK + ak8]) = *(u16x8*)av;
    *(u16x8*)(&Bs[brow*GLDK + bk16])     = vb0;
    *(u16x8*)(&Bs[brow*GLDK + bk16 + 8]) = vb1;
    __syncthreads();
    if (k0 + 32 < 1024){
      vb0 = *(const u16x8*)(W2mT + brow*1024 + k0 + 32 + bk16);
      vb1 = *(const u16x8*)(W2mT + brow*1024 + k0 + 32 + bk16 + 8);
    }
    bf16x8 af[2], bfv[4];
    #pragma unroll
    for (int m = 0; m < 2; m++)
      af[m] = *(const bf16x8*)(&As[(wm + m*16 + fr)*GLDK + fg*8]);
    #pragma unroll
    for (int n = 0; n < 4; n++)
      bfv[n] = *(const bf16x8*)(&Bs[(wn + n*16 + fr)*GLDK + fg*8]);
    #pragma unroll
    for (int m = 0; m < 2; m++)
      #pragma unroll
      for (int n = 0; n < 4; n++)
        acc[m][n] = __builtin_amdgcn_mfma_f32_16x16x32_bf16(af[m], bfv[n], acc[m][n], 0, 0, 0);
  }

  #pragma unroll
  for (int m = 0; m < 2; m++){
    #pragma unroll
    for (int n = 0; n < 4; n++){
      int col = wn + n*16 + fr;
      float bb = b2[col];
      #pragma unroll
      for (int j = 0; j < 4; j++){
        int node = n0 + wm + m*16 + fg*4 + j;
        int b = node/17, jj = node%17;
        float val = (acc[m][n][j] + bb)*sc + shv;
        fb[(((size_t)(p*128+b))*12 + t)*2432 + jj*128 + col] = f2bf(val);
      }
    }
  }
}

// h2s = hcat_bf @ W2tb^T with A/B register prefetch; al2 epilogue per head-block.
#define PLDK 40
__global__ __launch_bounds__(256) void k_gat2sp(
    const ushort* __restrict__ hcat_bf,   // [448][1024] (rows >=408 garbage)
    const ushort* __restrict__ W2tb,      // [1024][1024]
    const float* __restrict__ a_s, const float* __restrict__ a_d,
    float* __restrict__ h2s,              // [408][1024]
    float* __restrict__ al_s_p, float* __restrict__ al_d_p)
{
  __shared__ ushort As[64*PLDK];
  __shared__ ushort Bs[128*PLDK];
  __shared__ float alred[64][2][2];
  int tid = threadIdx.x;
  int bm = blockIdx.y * 64;
  int bn = blockIdx.x * 128;
  int hh = blockIdx.x;
  int wave = tid >> 6, lane = tid & 63;
  int wm = (wave >> 1)*32, wn = (wave & 1)*64;
  int fr = lane & 15, fg = lane >> 4;
  int arow = tid >> 2, ak8 = (tid & 3)*8;
  int brow = tid >> 1, bk16 = (tid & 1)*16;

  f32x4 acc[2][4];
  #pragma unroll
  for (int m = 0; m < 2; m++)
    #pragma unroll
    for (int n = 0; n < 4; n++) acc[m][n] = (f32x4){0.f,0.f,0.f,0.f};

  const ushort* ga = hcat_bf + (size_t)(bm+arow)*1024 + ak8;
  const ushort* gb = W2tb + (size_t)(bn+brow)*1024 + bk16;
  u16x8 va  = *(const u16x8*)ga;
  u16x8 vb0 = *(const u16x8*)gb;
  u16x8 vb1 = *(const u16x8*)(gb + 8);

  for (int k0 = 0; k0 < 1024; k0 += 32){
    if (k0) __syncthreads();
    *(u16x8*)(&As[arow*PLDK + ak8]) = va;
    *(u16x8*)(&Bs[brow*PLDK + bk16])     = vb0;
    *(u16x8*)(&Bs[brow*PLDK + bk16 + 8]) = vb1;
    __syncthreads();
    if (k0 + 32 < 1024){
      va  = *(const u16x8*)(ga + k0 + 32);
      vb0 = *(const u16x8*)(gb + k0 + 32);
      vb1 = *(const u16x8*)(gb + k0 + 40);
    }
    bf16x8 af[2], bfv[4];
    #pragma unroll
    for (int m = 0; m < 2; m++)
      af[m] = *(const bf16x8*)(&As[(wm + m*16 + fr)*PLDK + fg*8]);
    #pragma unroll
    for (int n = 0; n < 4; n++)
      bfv[n] = *(const bf16x8*)(&Bs[(wn + n*16 + fr)*PLDK + fg*8]);
    #pragma unroll
    for (int m = 0; m < 2; m++)
      #pragma unroll
      for (int n = 0; n < 4; n++)
        acc[m][n] = __builtin_amdgcn_mfma_f32_16x16x32_bf16(af[m], bfv[n], acc[m][n], 0, 0, 0);
  }

  #pragma unroll
  for (int m = 0; m < 2; m++){
    #pragma unroll
    for (int n = 0; n < 4; n++){
      int col = bn + wn + n*16 + fr;
      #pragma unroll
      for (int j = 0; j < 4; j++){
        int row = bm + wm + m*16 + fg*4 + j;
        if (row < 408) h2s[(size_t)row*1024 + col] = acc[m][n][j];
      }
    }
  }

  float avs[4], avd[4];
  #pragma unroll
  for (int n = 0; n < 4; n++){
    avs[n] = a_s[hh*128 + wn + n*16 + fr];
    avd[n] = a_d[hh*128 + wn + n*16 + fr];
  }
  #pragma unroll
  for (int m = 0; m < 2; m++){
    #pragma unroll
    for (int j = 0; j < 4; j++){
      float ps = 0.f, pd = 0.f;
      #pragma unroll
      for (int n = 0; n < 4; n++){
        ps += acc[m][n][j]*avs[n];
        pd += acc[m][n][j]*avd[n];
      }
      #pragma unroll
      for (int off = 1; off < 16; off <<= 1){
        ps += __shfl_xor(ps, off, 64);
        pd += __shfl_xor(pd, off, 64);
      }
      if (fr == 0){
        int rl = wm + m*16 + fg*4 + j;
        alred[rl][wave & 1][0] = ps;
        alred[rl][wave & 1][1] = pd;
      }
    }
  }
  __syncthreads();
  if (tid < 128){
    int rl = tid & 63, kind = tid >> 6;
    int grow = bm + rl;
    if (grow < 408){
      float v = alred[rl][0][kind] + alred[rl][1][kind];
      int p = grow / 204, tn = grow % 204;
      (kind ? al_d_p : al_s_p)[p*2048 + tn*8 + hh] = v;
    }
  }
}

// layer-2 aggregation + head mean + BN + bf16 write (overwrites fb rows of b=0)
__global__ void k_gat2_agg(const float* __restrict__ h2s_p, const float* __restrict__ al_s_p,
    const float* __restrict__ al_d_p, const float* __restrict__ b2,
    const float* __restrict__ bn_g, const float* __restrict__ bn_b,
    const float* __restrict__ bn_m, const float* __restrict__ bn_v,
    ushort* __restrict__ fb){
  int p = blockIdx.x / 204, r = blockIdx.x % 204;
  const float* h2s = h2s_p + p*208896;
  const float* al_s = al_s_p + p*2048;
  const float* al_d = al_d_p + p*2048;
  int t = r/17, dst = r%17;
  int base = t*17, c = threadIdx.x;             // 128 threads
  float sum = 0.f;
  for (int h = 0; h < 8; h++){
    float ad = al_d[(base+dst)*8 + h];
    float eself = lrelu02(al_s[(base+dst)*8 + h] + ad);
    float m = eself;
    for (int e = 0; e < 38; e++) if (d_c1[e] == dst)
      m = fmaxf(m, lrelu02(al_s[(base+d_c0[e])*8 + h] + ad));
    float w = __expf(eself - m), den = w;
    float acc = w * h2s[(base+dst)*1024 + h*128 + c];
    for (int e = 0; e < 38; e++) if (d_c1[e] == dst){
      float v = __expf(lrelu02(al_s[(base+d_c0[e])*8 + h] + ad) - m);
      den += v;
      acc += v * h2s[(base+d_c0[e])*1024 + h*128 + c];
    }
    sum += acc/den;
  }
  float inv = rsqrtf(bn_v[t] + 1e-5f);
  float sc = inv*bn_g[t], shv = bn_b[t] - bn_m[t]*sc;
  float val = (sum*0.125f + b2[c])*sc + shv;
  fb[(((size_t)(p*128))*12 + t)*2432 + dst*128 + c] = f2bf(val);
}

// bf16 MFMA projection GEMM with global_load_lds staging; bf16 output (pre_bf)
__global__ __launch_bounds__(256) void k_proj_mfma(
    const ushort* __restrict__ Abf,   // [3072][2432]
    const ushort* __restrict__ Wbf,   // [2][2048][2432]
    const float* __restrict__ bih_f, const float* __restrict__ bhh_f,
    const float* __restrict__ bih_b, const float* __restrict__ bhh_b,
    ushort* __restrict__ pre_bf)
{
  __shared__ ushort As[128*32];       // linear [row][k], 64 B rows
  __shared__ ushort Bs[128*32];
  int tid = threadIdx.x;
  int bm = blockIdx.y * 128;
  int dir = blockIdx.x >> 4;
  int bn = (blockIdx.x & 15) * 128;
  const ushort* W = Wbf + (size_t)dir * (2048*2432);
  const float* bi = dir ? bih_b : bih_f;
  const float* bh = dir ? bhh_b : bhh_f;
  ushort* C = pre_bf + (size_t)dir * 6291456;

  int wave = tid >> 6, lane = tid & 63;
  int wm = (wave >> 1) * 64, wn = (wave & 1) * 64;
  int fr = lane & 15, fg = lane >> 4;

  int grow = tid >> 2, gks = (tid & 3) * 8;
  const ushort* gaBase = Abf + (size_t)(bm + grow)*2432 + gks;
  const ushort* gbBase = W   + (size_t)(bn + grow)*2432 + gks;
  ushort* ldsA0 = &As[(wave*16)*32];
  ushort* ldsA1 = &As[(64 + wave*16)*32];
  ushort* ldsB0 = &Bs[(wave*16)*32];
  ushort* ldsB1 = &Bs[(64 + wave*16)*32];

  f32x4 acc[4][4];
  #pragma unroll
  for (int i = 0; i < 4; i++)
    #pragma unroll
    for (int j = 0; j < 4; j++) acc[i][j] = (f32x4){0.f,0.f,0.f,0.f};

  for (int k0 = 0; k0 < 2432; k0 += 32){
    __syncthreads();
    llds16(gaBase + k0,             ldsA0);
    llds16(gaBase + k0 + 64*2432,   ldsA1);
    llds16(gbBase + k0,             ldsB0);
    llds16(gbBase + k0 + 64*2432,   ldsB1);
    __syncthreads();
    bf16x8 af[4], bfv[4];
    #pragma unroll
    for (int m = 0; m < 4; m++)
      af[m] = *(const bf16x8*)(&As[(wm + m*16 + fr)*32 + fg*8]);
    #pragma unroll
    for (int n = 0; n < 4; n++)
      bfv[n] = *(const bf16x8*)(&Bs[(wn + n*16 + fr)*32 + fg*8]);
    #pragma unroll
    for (int m = 0; m < 4; m++)
      #pragma unroll
      for (int n = 0; n < 4; n++)
        acc[m][n] = __builtin_amdgcn_mfma_f32_16x16x32_bf16(af[m], bfv[n], acc[m][n], 0, 0, 0);
  }

  #pragma unroll
  for (int m = 0; m < 4; m++){
    #pragma unroll
    for (int n = 0; n < 4; n++){
      int col = bn + wn + n*16 + fr;
      float bsum = bi[col] + bh[col];
      #pragma unroll
      for (int j = 0; j < 4; j++){
        int row = bm + wm + m*16 + fg*4 + j;
        C[(size_t)row*2048 + col] = f2bf(acc[m][n][j] + bsum);
      }
    }
  }
}

// fused LSTM step: 512 threads / 8 waves; waves split K into two halves.
// A glds-staged (wave-private rows); B from fragment-packed Whh with 1-deep
// register prefetch; ONE barrier per K-chunk (no cross-wave LDS sharing).
__global__ __launch_bounds__(512) void k_lstm_step(
    ushort* __restrict__ hbf, const ushort* __restrict__ Whh_pk,
    const ushort* __restrict__ pre_bf, float* __restrict__ cbuf,
    float* __restrict__ lout, int s)
{
  int dir = blockIdx.z;
  int bm = blockIdx.y * 64;
  int bn = blockIdx.x * 64;
  int tCur = dir ? (11 - s) : s;
  int tid = threadIdx.x, wave = tid >> 6, lane = tid & 63;
  int kg = wave >> 2, wv = wave & 3;
  int fr = lane & 15, fg = lane >> 4;
  __shared__ ushort As[2][64*32];
  __shared__ float sg[64][68];
  f32x4 acc[4];
  #pragma unroll
  for (int n = 0; n < 4; n++) acc[n] = (f32x4){0.f,0.f,0.f,0.f};

  if (s > 0){
    const ushort* hA = hbf + ((size_t)((s&1)*2 + dir))*131072;
    int rsub = lane >> 2, kl = (lane & 3)*8;
    const ushort* gA = hA + (size_t)(bm + wv*16 + rsub)*512 + kg*256 + kl;
    ushort* lA = &As[kg][(wv*16)*32];
    const ushort* wb = Whh_pk + (size_t)dir*1048576
                     + (size_t)blockIdx.x*32768 + kg*16384 + lane*8;
    bf16x8 nb0 = *(const bf16x8*)(wb);
    bf16x8 nb1 = *(const bf16x8*)(wb + 512);
    bf16x8 nb2 = *(const bf16x8*)(wb + 1024);
    bf16x8 nb3 = *(const bf16x8*)(wb + 1536);
    #pragma unroll
    for (int kk = 0; kk < 8; kk++){
      __builtin_amdgcn_sched_barrier(0);     // keep llds16 after prior MFMA waits
      llds16(gA + kk*32, lA);
      bf16x8 b0 = nb0, b1 = nb1, b2 = nb2, b3 = nb3;
      if (kk < 7){
        nb0 = *(const bf16x8*)(wb + (kk+1)*2048);
        nb1 = *(const bf16x8*)(wb + (kk+1)*2048 + 512);
        nb2 = *(const bf16x8*)(wb + (kk+1)*2048 + 1024);
        nb3 = *(const bf16x8*)(wb + (kk+1)*2048 + 1536);
      }
      __syncthreads();                       // drains glds; As rows now valid
      bf16x8 af = *(const bf16x8*)(&As[kg][(wv*16 + fr)*32 + fg*8]);
      acc[0] = __builtin_amdgcn_mfma_f32_16x16x32_bf16(af, b0, acc[0], 0, 0, 0);
      acc[1] = __builtin_amdgcn_mfma_f32_16x16x32_bf16(af, b1, acc[1], 0, 0, 0);
      acc[2] = __builtin_amdgcn_mfma_f32_16x16x32_bf16(af, b2, acc[2], 0, 0, 0);
      acc[3] = __builtin_amdgcn_mfma_f32_16x16x32_bf16(af, b3, acc[3], 0, 0, 0);
    }
    __syncthreads();
  }
  if (kg == 0){
    #pragma unroll
    for (int n = 0; n < 4; n++)
      #pragma unroll
      for (int j = 0; j < 4; j++)
        sg[wv*16 + fg*4 + j][n*16 + fr] = acc[n][j];
  }
  __syncthreads();
  if (kg == 1){
    #pragma unroll
    for (int n = 0; n < 4; n++)
      #pragma unroll
      for (int j = 0; j < 4; j++)
        sg[wv*16 + fg*4 + j][n*16 + fr] += acc[n][j];
  }
  __syncthreads();

  int ul = tid & 15, rb = tid >> 4;
  int u = (bn >> 2) + ul;
  ushort* hw = hbf + ((size_t)(((s&1)^1)*2 + dir))*131072;
  #pragma unroll
  for (int q = 0; q < 2; q++){
    int r = rb + q*32, b = bm + r;
    const ushort* pb = pre_bf + (size_t)dir*6291456 + ((size_t)b*12 + tCur)*2048;
    float gi = sg[r][ul*4+0] + bf2f(pb[u]);
    float gf = sg[r][ul*4+1] + bf2f(pb[512+u]);
    float gg = sg[r][ul*4+2] + bf2f(pb[1024+u]);
    float go = sg[r][ul*4+3] + bf2f(pb[1536+u]);
    float cP = (s > 0) ? cbuf[dir*131072 + b*512 + u] : 0.f;
    float cN = sigmoidf_(gf)*cP + sigmoidf_(gi)*tanhf(gg);
    float h = sigmoidf_(go)*tanhf(cN);
    cbuf[dir*131072 + b*512 + u] = cN;
    lout[((size_t)b*12 + tCur)*1024 + dir*512 + u] = h;
    hw[(size_t)b*512 + u] = f2bf(h);
  }
}

// fp32 GEMM, 32x32 tiles (high block count for small tail GEMMs):
// C[M,N] = A[M,K] @ B[N,K]^T (+bias)
__global__ __launch_bounds__(256) void k_gemm32(
    const float* __restrict__ A, int lda,
    const float* __restrict__ B, int ldb,
    float* __restrict__ C, int ldc,
    int M, int N, int K,
    const float* __restrict__ bias1)
{
  __shared__ float As[16][36];
  __shared__ float Bs[16][36];
  int tid = threadIdx.x;
  int bm = blockIdx.y*32, bn = blockIdx.x*32;
  int half = tid >> 7, t = tid & 127;
  int lr = t >> 2, lkq = (t & 3) * 4;
  int tx = tid & 15, ty = tid >> 4;
  float acc[2][2] = {{0.f,0.f},{0.f,0.f}};
  for (int k0 = 0; k0 < K; k0 += 16){
    float4 v = make_float4(0.f,0.f,0.f,0.f);
    if (half == 0){ int r = bm + lr; if (r < M) v = *(const float4*)(A + (size_t)r*lda + k0 + lkq); }
    else          { int r = bn + lr; if (r < N) v = *(const float4*)(B + (size_t)r*ldb + k0 + lkq); }
    if (k0) __syncthreads();
    if (half == 0){ As[lkq+0][lr]=v.x; As[lkq+1][lr]=v.y; As[lkq+2][lr]=v.z; As[lkq+3][lr]=v.w; }
    else          { Bs[lkq+0][lr]=v.x; Bs[lkq+1][lr]=v.y; Bs[lkq+2][lr]=v.z; Bs[lkq+3][lr]=v.w; }
    __syncthreads();
    #pragma unroll
    for (int kk = 0; kk < 16; kk++){
      float a0 = As[kk][ty*2], a1 = As[kk][ty*2+1];
      float b0 = Bs[kk][tx*2], b1 = Bs[kk][tx*2+1];
      acc[0][0] += a0*b0; acc[0][1] += a0*b1;
      acc[1][0] += a1*b0; acc[1][1] += a1*b1;
    }
  }
  #pragma unroll
  for (int i = 0; i < 2; i++){
    int r = bm + ty*2 + i;
    if (r >= M) continue;
    #pragma unroll
    for (int j = 0; j < 2; j++){
      int cc = bn + tx*2 + j;
      if (cc >= N) continue;
      float v = acc[i][j];
      if (bias1) v += bias1[cc];
      C[(size_t)r*ldc + cc] = v;
    }
  }
}

// temporal attention pool
__global__ __launch_bounds__(256) void k_attention(const float* __restrict__ lout,
    const float* __restrict__ W_att, float* __restrict__ attended){
  int b = blockIdx.x, tid = threadIdx.x;
  __shared__ float part[256*12];
  __shared__ float sc[12];
  float p[12];
  #pragma unroll
  for (int t = 0; t < 12; t++) p[t] = 0.f;
  #pragma unroll
  for (int j = 0; j < 4; j++){
    int c = tid + j*256;
    float w = W_att[c];
    #pragma unroll
    for (int t = 0; t < 12; t++) p[t] += lout[((size_t)b*12 + t)*1024 + c] * w;
  }
  #pragma unroll
  for (int t = 0; t < 12; t++) part[tid*12 + t] = p[t];
  __syncthreads();
  if (tid < 12){
    float s = 0.f;
    for (int i = 0; i < 256; i++) s += part[i*12 + tid];
    sc[tid] = s;
  }
  __syncthreads();
  float m = sc[0];
  #pragma unroll
  for (int t = 1; t < 12; t++) m = fmaxf(m, sc[t]);
  float wt[12], den = 0.f;
  #pragma unroll
  for (int t = 0; t < 12; t++){ wt[t] = __expf(sc[t] - m); den += wt[t]; }
  float inv = 1.f/den;
  #pragma unroll
  for (int j = 0; j < 4; j++){
    int c = tid + j*256;
    float a = 0.f;
    #pragma unroll
    for (int t = 0; t < 12; t++) a += wt[t]*lout[((size_t)b*12 + t)*1024 + c];
    attended[(size_t)b*1024 + c] = a*inv;
  }
}

extern "C" void kernel_launch(void* const* d_in, const int* in_sizes, int n_in,
                              void* d_out, int out_size, void* d_ws, size_t ws_size,
                              hipStream_t stream)
{
  const float* pose1 = (const float*)d_in[0];
  const float* pose2 = (const float*)d_in[1];
  const float* W1    = (const float*)d_in[2];
  const float* a_src1= (const float*)d_in[3];
  const float* a_dst1= (const float*)d_in[4];
  const float* b1    = (const float*)d_in[5];
  const float* W2    = (const float*)d_in[6];
  const float* a_src2= (const float*)d_in[7];
  const float* a_dst2= (const float*)d_in[8];
  const float* b2    = (const float*)d_in[9];
  const float* W_fc  = (const float*)d_in[10];
  const float* b_fc  = (const float*)d_in[11];
  const float* bn_g  = (const float*)d_in[12];
  const float* bn_b  = (const float*)d_in[13];
  const float* bn_m  = (const float*)d_in[14];
  const float* bn_v  = (const float*)d_in[15];
  const float* Wih_f = (const float*)d_in[16];
  const float* Whh_f = (const float*)d_in[17];
  const float* bih_f = (const float*)d_in[18];
  const float* bhh_f = (const float*)d_in[19];
  const float* Wih_b = (const float*)d_in[20];
  const float* Whh_b = (const float*)d_in[21];
  const float* bih_b = (const float*)d_in[22];
  const float* bhh_b = (const float*)d_in[23];
  const float* W_att = (const float*)d_in[24];
  const float* W_cls = (const float*)d_in[26];
  const float* b_cls = (const float*)d_in[27];
  (void)in_sizes; (void)n_in; (void)out_size; (void)ws_size;

  float* ws = (float*)d_ws;
  // weight region (7,471,104 f), written once by k_front1:
  ushort* Wbf     = (ushort*)ws;                     // 9,961,472 u
  ushort* Whh_pk  = (ushort*)(ws + 4980736);         // 2,097,152 u (fragment-packed)
  ushort* W2tb    = (ushort*)(ws + 6029312);         // 1,048,576 u
  ushort* W2mT    = (ushort*)(ws + 6553600);         // 131,072 u
  ushort* pre_bf  = (ushort*)(ws + 7471104);         // [2][3072][2048] u
  float* rawh_p   = ws + 7471104;                    // 2x208,896 f (dead before proj)
  float* R        = ws + 20054016;                   // phase-multiplexed
  // GAT phase in R:
  ushort* fb      = (ushort*)R;                      // [3072][2432] bf16
  float* h2s      = R + 3735552;                     // [408][1024] f
  ushort* hcat_bf = (ushort*)(R + 4153344);          // [448][1024] u
  float* alB      = R + 4382720;                     // 16,384 f
  float* al1s = alB, *al1d = alB + 4096, *al2s = alB + 8192, *al2d = alB + 12288;
  // LSTM phase in R (fb dead after proj):
  ushort* hbf = (ushort*)R;
  float* cbuf = R + 262144;
  float* lout = R + 524288;

  float* attended = (float*)d_out;                   // [256][1024]
  float* logits   = attended + 262144;               // [256][500]

  k_front1<<<15000, 256, 0, stream>>>(W2, Wih_f, Wih_b, Whh_f, Whh_b,
      pose1, pose2, W1, a_src1, a_dst1, W_fc, b_fc,
      bn_g, bn_b, bn_m, bn_v,
      W2mT, W2tb, Wbf, Whh_pk, rawh_p, al1s, al1d, fb);

  k_front2<<<1224, 256, 0, stream>>>(pose1, pose2, W1, b1, W2mT, b2,
      bn_g, bn_b, bn_m, bn_v, rawh_p, al1s, al1d, hcat_bf, fb);

  k_gat2sp<<<dim3(8,7), 256, 0, stream>>>(hcat_bf, W2tb, a_src2, a_dst2,
                                          h2s, al2s, al2d);
  k_gat2_agg<<<408, 128, 0, stream>>>(h2s, al2s, al2d, b2,
                                      bn_g, bn_b, bn_m, bn_v, fb);

  k_proj_mfma<<<dim3(32, 24), 256, 0, stream>>>(fb, Wbf,
      bih_f, bhh_f, bih_b, bhh_b, pre_bf);

  for (int s = 0; s < 12; s++)
    k_lstm_step<<<dim3(32,4,2), 512, 0, stream>>>(hbf, Whh_pk, pre_bf, cbuf, lout, s);

  k_attention<<<256, 256, 0, stream>>>(lout, W_att, attended);
  k_gemm32<<<dim3(16,8), 256, 0, stream>>>(attended, 1024, W_cls, 1024, logits, 500,
                                           256, 500, 1024, b_cls);
}